// Round 9
// baseline (594.654 us; speedup 1.0000x reference)
//
#include <hip/hip_runtime.h>
#include <math.h>
#include <stdint.h>

// AIS estimator: N=1024 samples, B=128, DIM=DX=64, K=16 anneal steps, 3 leapfrog.
// Round 24: ORIGINAL-BASIS leapfrog -- k_eig deleted. With q' = q - mu:
//   g = bk*(f - q'A) - q'        (f = WS_F, bit-identical setup2 math)
//   w = wconst + q'.f - 0.5*q'.(q'A)   (wconst bit-identical setup3 math)
// y = q'A computed by the validated f16-hi/lo 3-term MFMA (A as B-operand,
// packed like V was). 3 matvecs/step (sub1 reuses prev w-eval's y). p is used
// RAW (no rotation MFMA, no draw-splitting; draws feed p as f32 directly).
// y comes out in MFMA C-layout -> per-wave LDS transpose (pad-68 rows,
// 2-way-conflict-free; in-wave s_waitcnt lgkmcnt(0), no barrier).
// Deleted: k_eig (~225us critical path), RNG producer, all staging (r23
// lesson: staging saves only ~10us/step and bytes were exhausted; pn staging
// costs ~20us harness re-poison), fz/V/lam, k_fused. 4 launches total.
// State per lane (A-frag layout): traj = lane&15, d = (lane>>4)*8+[0..8)
// and 32+... ; q',p,f,y = 16 f32 each. RNG indices unchanged (bit-exact).

#define WS_A     0
#define WS_MU    4096
#define WS_C     12288
#define WS_XSQ   20480
#define WS_AMU   20608
#define WS_F     28800
#define WS_WC    36992
#define WS_V     37120
#define WS_LAM   41216
#define WS_FZ    41280
#define WS_VF    49472
#define WS_SLW   53568
#define WS_TOTAL (WS_SLW + 131072)

#define LOG2PI 1.8378770664093453f

typedef _Float16 half8_t __attribute__((ext_vector_type(8)));
typedef float f4_t __attribute__((ext_vector_type(4)));
typedef unsigned int uint4_t __attribute__((ext_vector_type(4)));

struct KParams {
  float beta[18];
  float dbeta[17];
  uint32_t fk0[16];
  uint32_t fk1[16];
};

__host__ __device__ static inline void threefry2x32(uint32_t ks0, uint32_t ks1,
                                                    uint32_t x0, uint32_t x1,
                                                    uint32_t& o0, uint32_t& o1) {
  uint32_t ks2 = ks0 ^ ks1 ^ 0x1BD11BDAu;
  x0 += ks0; x1 += ks1;
#define TFR(r) { x0 += x1; x1 = (x1 << (r)) | (x1 >> (32 - (r))); x1 ^= x0; }
  TFR(13) TFR(15) TFR(26) TFR(6)
  x0 += ks1; x1 += ks2 + 1u;
  TFR(17) TFR(29) TFR(16) TFR(24)
  x0 += ks2; x1 += ks0 + 2u;
  TFR(13) TFR(15) TFR(26) TFR(6)
  x0 += ks0; x1 += ks1 + 3u;
  TFR(17) TFR(29) TFR(16) TFR(24)
  x0 += ks1; x1 += ks2 + 4u;
  TFR(13) TFR(15) TFR(26) TFR(6)
  x0 += ks2; x1 += ks0 + 5u;
#undef TFR
  o0 = x0; o1 = x1;
}

__device__ __forceinline__ float u_from_bits(uint32_t bits) {
  const float LO = __uint_as_float(0xBF7FFFFFu);  // nextafter(-1,0) in f32
  float f = __uint_as_float((bits >> 9) | 0x3F800000u) - 1.0f;
  return fmaf(f, 2.0f, LO);
}

// XLA ErfInv32 (Giles); __logf variant validated r11-r14 (absmax = 1 bf16 ulp)
__device__ __forceinline__ float erfinv_f(float x) {
  float w = -__logf(fmaf(-x, x, 1.0f));
  float p;
  if (w < 5.0f) {
    w -= 2.5f;
    p = 2.81022636e-08f;
    p = fmaf(p, w, 3.43273939e-07f);
    p = fmaf(p, w, -3.5233877e-06f);
    p = fmaf(p, w, -4.39150654e-06f);
    p = fmaf(p, w, 0.00021858087f);
    p = fmaf(p, w, -0.00125372503f);
    p = fmaf(p, w, -0.00417768164f);
    p = fmaf(p, w, 0.246640727f);
    p = fmaf(p, w, 1.50140941f);
  } else {
    w = sqrtf(w) - 3.0f;
    p = -0.000200214257f;
    p = fmaf(p, w, 0.000100950558f);
    p = fmaf(p, w, 0.00134934322f);
    p = fmaf(p, w, -0.00367342844f);
    p = fmaf(p, w, 0.00573950773f);
    p = fmaf(p, w, -0.0076224613f);
    p = fmaf(p, w, 0.00943887047f);
    p = fmaf(p, w, 1.00167406f);
    p = fmaf(p, w, 2.83297682f);
  }
  return p * x;
}

// ---- setup1: A = Wdec Wdec^T ; mu[b][d] ; c[b][d] ; xsq[b]
__global__ void k_setup1(const float* __restrict__ x, const float* __restrict__ Wenc,
                         const float* __restrict__ Wdec, float* __restrict__ ws) {
  int t = blockIdx.x * 256 + threadIdx.x;
  if (t < 4096) {
    int i = t >> 6, j = t & 63;
    float s = 0;
    for (int e = 0; e < 64; ++e) s = fmaf(Wdec[i*64+e], Wdec[j*64+e], s);
    ws[WS_A + t] = s;
  } else if (t < 12288) {
    int u = t - 4096; int b = u >> 6, d = u & 63;
    float s = 0;
    for (int e = 0; e < 64; ++e) s = fmaf(x[b*64+e], Wenc[e*64+d], s);
    ws[WS_MU + u] = s;
  } else if (t < 20480) {
    int u = t - 12288; int b = u >> 6, d = u & 63;
    float s = 0;
    for (int e = 0; e < 64; ++e) s = fmaf(x[b*64+e], Wdec[d*64+e], s);
    ws[WS_C + u] = s;
  } else if (t < 20608) {
    int b = t - 20480;
    float s = 0;
    for (int e = 0; e < 64; ++e) s = fmaf(x[b*64+e], x[b*64+e], s);
    ws[WS_XSQ + b] = s;
  }
}

// ---- setup2x: blocks 0-31: F[b][d] = c - mu - (mu A)[d] (amu inline,
// same loop order as old setup2 -> bit-identical); blocks 32-35: pack A into
// f16 hi/lo MFMA B-fragments at WS_VF (same packing as V was; A symmetric);
// block 36: wconst[b] (amu inline, same order as old setup2+setup3).
__global__ void k_setup2x(float* __restrict__ ws) {
  int blk = blockIdx.x;
  if (blk < 32) {
    int t = blk * 256 + threadIdx.x;
    int b = t >> 6, d = t & 63;
    float s = 0;
    for (int m = 0; m < 64; ++m) s = fmaf(ws[WS_MU + b*64+m], ws[WS_A + m*64+d], s);
    ws[WS_F + t] = ws[WS_C + t] - ws[WS_MU + t] - s;
  } else if (blk < 36) {
    int idx = (blk - 32) * 256 + threadIdx.x;   // 0..1023
    int lane = idx & 63, F = idx >> 6;
    int t = F >> 3, kt = (F >> 2) & 1, nt = F & 3;
    int n = nt*16 + (lane & 15);
    int k0 = kt*32 + ((lane >> 4) & 3)*8;
    uint32_t out[4];
    for (int jj = 0; jj < 4; ++jj) {
      float v0 = ws[WS_A + (k0 + 2*jj    )*64 + n];
      float v1 = ws[WS_A + (k0 + 2*jj + 1)*64 + n];
      _Float16 h0, h1;
      if (t == 0) { h0 = (_Float16)v0; h1 = (_Float16)v1; }
      else {
        _Float16 a0 = (_Float16)v0, a1 = (_Float16)v1;
        h0 = (_Float16)(v0 - (float)a0);
        h1 = (_Float16)(v1 - (float)a1);
      }
      unsigned short u0 = __builtin_bit_cast(unsigned short, h0);
      unsigned short u1 = __builtin_bit_cast(unsigned short, h1);
      out[jj] = (uint32_t)u0 | ((uint32_t)u1 << 16);
    }
    uint32_t* dst = (uint32_t*)ws + WS_VF + idx*4;
    dst[0] = out[0]; dst[1] = out[1]; dst[2] = out[2]; dst[3] = out[3];
  } else {
    int b = threadIdx.x;
    if (b < 128) {
      float muc = 0, musq = 0, muamu = 0;
      for (int d = 0; d < 64; ++d) {
        float am = 0;
        for (int m = 0; m < 64; ++m) am = fmaf(ws[WS_MU + b*64+m], ws[WS_A + m*64+d], am);
        float mm = ws[WS_MU + b*64+d];
        muc   = fmaf(mm, ws[WS_C + b*64+d], muc);
        musq  = fmaf(mm, mm, musq);
        muamu = fmaf(mm, am, muamu);
      }
      ws[WS_WC + b] = -32.0f * LOG2PI - 0.5f * ws[WS_XSQ + b]
                      + muc - 0.5f * musq - 0.5f * muamu;
    }
  }
}

// ---- k_main macros ---------------------------------------------------------

#define DRAW(PC, IDX)                                                        \
  { uint32_t o0, o1;                                                         \
    threefry2x32(k0, k1, 0u, base + (IDX), o0, o1);                          \
    PC = 1.41421356f * erfinv_f(u_from_bits(o0 ^ o1)); }

#define SPLIT1(AH, AL, J, VV)                                                \
  { _Float16 hh = (_Float16)(VV); AH[J] = hh;                                \
    AL[J] = (_Float16)((VV) - (float)hh); }

#define FRAGB(T, KT, NT)                                                     \
  __builtin_bit_cast(half8_t, VF[(((T)*2+(KT))*4+(NT))*64 + lane])

#define ROT1(ZO, NT, AH0, AL0, AH1, AL1)                                     \
  { half8_t bh0 = FRAGB(0,0,NT), bh1 = FRAGB(0,1,NT);                        \
    half8_t bl0 = FRAGB(1,0,NT), bl1 = FRAGB(1,1,NT);                        \
    f4_t aa = {0.f, 0.f, 0.f, 0.f};                                          \
    aa = __builtin_amdgcn_mfma_f32_16x16x32_f16(AH0, bh0, aa, 0, 0, 0);      \
    aa = __builtin_amdgcn_mfma_f32_16x16x32_f16(AH1, bh1, aa, 0, 0, 0);      \
    aa = __builtin_amdgcn_mfma_f32_16x16x32_f16(AL0, bh0, aa, 0, 0, 0);      \
    aa = __builtin_amdgcn_mfma_f32_16x16x32_f16(AL1, bh1, aa, 0, 0, 0);      \
    aa = __builtin_amdgcn_mfma_f32_16x16x32_f16(AH0, bl0, aa, 0, 0, 0);      \
    aa = __builtin_amdgcn_mfma_f32_16x16x32_f16(AH1, bl1, aa, 0, 0, 0);      \
    ZO = aa; }

// transpose-write one C-layout tile (cols nt*16+dlow, rows 4 trajs) to LDS
#define TRY(NT, YC)                                                          \
  { int d_ = (NT)*16 + dlow;                                                 \
    TRS[(tq4+0)*68 + d_] = YC.x; TRS[(tq4+1)*68 + d_] = YC.y;                \
    TRS[(tq4+2)*68 + d_] = YC.z; TRS[(tq4+3)*68 + d_] = YC.w; }

// y = q'A : split q' -> 24 MFMA (3-term) -> LDS transpose -> y0..y3 (A-layout)
#define COMPY                                                                \
  { half8_t ah0, al0, ah1, al1;                                              \
    SPLIT1(ah0, al0, 0, qv0.x) SPLIT1(ah0, al0, 1, qv0.y)                    \
    SPLIT1(ah0, al0, 2, qv0.z) SPLIT1(ah0, al0, 3, qv0.w)                    \
    SPLIT1(ah0, al0, 4, qv1.x) SPLIT1(ah0, al0, 5, qv1.y)                    \
    SPLIT1(ah0, al0, 6, qv1.z) SPLIT1(ah0, al0, 7, qv1.w)                    \
    SPLIT1(ah1, al1, 0, qv2.x) SPLIT1(ah1, al1, 1, qv2.y)                    \
    SPLIT1(ah1, al1, 2, qv2.z) SPLIT1(ah1, al1, 3, qv2.w)                    \
    SPLIT1(ah1, al1, 4, qv3.x) SPLIT1(ah1, al1, 5, qv3.y)                    \
    SPLIT1(ah1, al1, 6, qv3.z) SPLIT1(ah1, al1, 7, qv3.w)                    \
    f4_t yC0, yC1, yC2, yC3;                                                 \
    ROT1(yC0, 0, ah0, al0, ah1, al1) ROT1(yC1, 1, ah0, al0, ah1, al1)        \
    ROT1(yC2, 2, ah0, al0, ah1, al1) ROT1(yC3, 3, ah0, al0, ah1, al1)        \
    TRY(0, yC0) TRY(1, yC1) TRY(2, yC2) TRY(3, yC3)                          \
    asm volatile("s_waitcnt lgkmcnt(0)" ::: "memory");                       \
    yv0 = *(const f4_t*)&TRS[trow + koff];                                   \
    yv1 = *(const f4_t*)&TRS[trow + koff + 4];                               \
    yv2 = *(const f4_t*)&TRS[trow + 32 + koff];                              \
    yv3 = *(const f4_t*)&TRS[trow + 32 + koff + 4];                          \
    asm volatile("" ::: "memory"); }

// leapfrog: g = bk*(f - y) - q' ; p += .025g (x2 if DBL) ; q' += .05p
#define LFV(QV, PV, FV, YV, DBL)                                             \
  { f4_t tt = FV - YV;                                                       \
    f4_t gg = __builtin_elementwise_fma(bk4, tt, -QV);                       \
    PV = __builtin_elementwise_fma(c025v, gg, PV);                           \
    if (DBL) PV = __builtin_elementwise_fma(c025v, gg, PV);                  \
    QV = __builtin_elementwise_fma(c005v, PV, QV); }
#define SUBSTEP(DBL)                                                         \
  LFV(qv0, pv0, fv0, yv0, DBL) LFV(qv1, pv1, fv1, yv1, DBL)                  \
  LFV(qv2, pv2, fv2, yv2, DBL) LFV(qv3, pv3, fv3, yv3, DBL)

// w = wconst + q'.f - 0.5*q'.y ; d-sum = 16 lane-local + lanes {16,32}
#define WEV(WOUT)                                                            \
  { f4_t s1v = fv0*qv0 + fv1*qv1 + fv2*qv2 + fv3*qv3;                        \
    f4_t s2v = qv0*yv0 + qv1*yv1 + qv2*yv2 + qv3*yv3;                        \
    f4_t vv = s1v - 0.5f*s2v;                                                \
    float r_ = vv.x + vv.y + vv.z + vv.w;                                    \
    r_ += __shfl_xor(r_, 16);                                                \
    r_ += __shfl_xor(r_, 32);                                                \
    WOUT = r_ + wcs; }

// ---- main: original-basis leapfrog; wave = 16 trajs; 4 waves/block.
// State in A-frag layout: traj = lane&15, d = (lane>>4)*8+[0..8) and +32.
__global__ __launch_bounds__(256) void k_main(const float* __restrict__ qn,
                                              const float* __restrict__ ws,
                                              float* __restrict__ slw_out,
                                              KParams P) {
  __shared__ uint4_t VF[1024];        // 16 KB: A-hat f16 hi/lo B-fragments
  __shared__ float TR[4][16 * 68];    // 17 KB: per-wave transpose scratch
  const int tid = threadIdx.x;
  {
    const uint4_t* src = (const uint4_t*)((const uint32_t*)ws + WS_VF);
    for (int i = tid; i < 1024; i += 256) VF[i] = src[i];
  }
  __syncthreads();

  const int lane = tid & 63;
  const int wv = tid >> 6;
  const int trj = lane & 15;             // trajectory within wave
  const int g4 = lane >> 4;              // k-group
  const int koff = g4 * 8;               // d offset of this lane's components
  const int dlow = lane & 15;            // C-layout col (transpose write)
  const int tq4 = (lane >> 4) * 4;       // C-layout row base (transpose write)
  const int trow = trj * 68;             // transpose read row
  float* TRS = &TR[wv][0];
  const int trajBase = blockIdx.x * 64 + wv * 16;
  const uint32_t base = (uint32_t)(trajBase + trj) * 64u;  // RNG/state row
  const int b = (trajBase + trj) & 127;                    // batch col

  f4_t fv0, fv1, fv2, fv3;
  fv0 = *(const f4_t*)&ws[WS_F + b*64 + koff];
  fv1 = *(const f4_t*)&ws[WS_F + b*64 + koff + 4];
  fv2 = *(const f4_t*)&ws[WS_F + b*64 + 32 + koff];
  fv3 = *(const f4_t*)&ws[WS_F + b*64 + 32 + koff + 4];
  const float wcs = ws[WS_WC + b];
  const f4_t c025v = {0.025f, 0.025f, 0.025f, 0.025f};
  const f4_t c005v = {0.05f, 0.05f, 0.05f, 0.05f};

  f4_t qv0, qv1, qv2, qv3, pv0, pv1, pv2, pv3, yv0, yv1, yv2, yv3;
  float slw = 0.0f;

  // j = 0: q' = qn (A-layout load), y = q'A, w0
  {
    const float* qp = qn + (size_t)base;
    qv0 = *(const f4_t*)(qp + koff);
    qv1 = *(const f4_t*)(qp + koff + 4);
    qv2 = *(const f4_t*)(qp + 32 + koff);
    qv3 = *(const f4_t*)(qp + 32 + koff + 4);
  }
  COMPY
  {
    float w0;
    WEV(w0);
    slw = fmaf(P.dbeta[0], w0, slw);
  }

  for (int j = 1; j <= 16; ++j) {
    const float bk = P.beta[j];
    const f4_t bk4 = {bk, bk, bk, bk};
    const uint32_t k0 = P.fk0[j-1], k1 = P.fk1[j-1];
    // momentum resample: raw f32 draws, no rotation needed
    DRAW(pv0.x, koff + 0) DRAW(pv0.y, koff + 1)
    DRAW(pv0.z, koff + 2) DRAW(pv0.w, koff + 3)
    DRAW(pv1.x, koff + 4) DRAW(pv1.y, koff + 5)
    DRAW(pv1.z, koff + 6) DRAW(pv1.w, koff + 7)
    DRAW(pv2.x, 32 + koff + 0) DRAW(pv2.y, 32 + koff + 1)
    DRAW(pv2.z, 32 + koff + 2) DRAW(pv2.w, 32 + koff + 3)
    DRAW(pv3.x, 32 + koff + 4) DRAW(pv3.y, 32 + koff + 5)
    DRAW(pv3.z, 32 + koff + 6) DRAW(pv3.w, 32 + koff + 7)
    // leapfrog: sub1 reuses y from previous w-eval (same q')
    SUBSTEP(false)
    COMPY
    SUBSTEP(true)
    COMPY
    SUBSTEP(true)
    COMPY                       // y at final q' -> w-eval + next step's sub1
    float wj;
    WEV(wj);
    slw = fmaf(P.dbeta[j], wj, slw);
  }
  if (lane < 16) slw_out[trajBase + lane] = slw;
}

// ---- logsumexp over n per batch column b
__global__ void k_reduce(const float* __restrict__ slw, float* __restrict__ out) {
  __shared__ float red[256];
  int b = blockIdx.x, t = threadIdx.x;
  float v0 = slw[t*128 + b];
  float v1 = slw[(t+256)*128 + b];
  float v2 = slw[(t+512)*128 + b];
  float v3 = slw[(t+768)*128 + b];
  float m = fmaxf(fmaxf(v0, v1), fmaxf(v2, v3));
  red[t] = m; __syncthreads();
  for (int s = 128; s > 0; s >>= 1) {
    if (t < s) red[t] = fmaxf(red[t], red[t+s]);
    __syncthreads();
  }
  m = red[0]; __syncthreads();
  float sum = expf(v0 - m) + expf(v1 - m) + expf(v2 - m) + expf(v3 - m);
  red[t] = sum; __syncthreads();
  for (int s = 128; s > 0; s >>= 1) {
    if (t < s) red[t] += red[t+s];
    __syncthreads();
  }
  if (t == 0) out[b] = m + logf(red[0]) - 6.93147180559945309f;  // - log(1024)
}

extern "C" void kernel_launch(void* const* d_in, const int* in_sizes, int n_in,
                              void* d_out, int out_size, void* d_ws, size_t ws_size,
                              hipStream_t stream) {
  const float* x    = (const float*)d_in[0];
  const float* Wenc = (const float*)d_in[1];
  const float* Wdec = (const float*)d_in[2];
  const float* qn   = (const float*)d_in[3];
  // d_in[4] (p_noise) is dead: momentum fully resampled every anneal step.
  float* ws  = (float*)d_ws;
  float* out = (float*)d_out;
  if (ws_size < (size_t)WS_TOTAL * sizeof(float)) return;

  KParams P;
  double bb[18];
  for (int i = 0; i < 18; ++i) {
    double tt = (double)i / 17.0;
    bb[i] = 1.0 / (1.0 + exp(-(8.0 * tt - 4.0)));
  }
  for (int i = 0; i < 18; ++i) P.beta[i] = (float)((bb[i] - bb[0]) / (bb[17] - bb[0]));
  for (int j = 0; j <= 16; ++j) P.dbeta[j] = P.beta[j+1] - P.beta[j];
  for (int k = 1; k <= 16; ++k) {
    uint32_t a, c;
    threefry2x32(0u, 42u, 0u, (uint32_t)k, a, c);  // fold_in(key(42), k)
    P.fk0[k-1] = a; P.fk1[k-1] = c;
  }

  hipLaunchKernelGGL(k_setup1, dim3(81), dim3(256), 0, stream, x, Wenc, Wdec, ws);
  hipLaunchKernelGGL(k_setup2x, dim3(37), dim3(256), 0, stream, ws);
  hipLaunchKernelGGL(k_main, dim3(2048), dim3(256), 0, stream, qn, ws, ws + WS_SLW, P);
  hipLaunchKernelGGL(k_reduce, dim3(128), dim3(256), 0, stream, ws + WS_SLW, out);
}